// Round 5
// baseline (714.227 us; speedup 1.0000x reference)
//
#include <hip/hip_runtime.h>
#include <cstddef>

#define T_LEN 512
#define IN_D 8
#define H 32
#define NBATCH 16        // batches per WG = 4 waves x 4 batches
#define NT 256           // 4 independent waves; NO barriers in the loop
#define LOG2E 1.44269504088896341f
#define CSCLAMP 88.f

typedef __attribute__((ext_vector_type(8))) short bf16x8;
typedef __attribute__((ext_vector_type(4))) float f32x4;
typedef __attribute__((ext_vector_type(4))) unsigned u32x4;

__device__ __forceinline__ float fexp2(float v) { return __builtin_amdgcn_exp2f(v); }
__device__ __forceinline__ float frcp(float v)  { return __builtin_amdgcn_rcpf(v); }
__device__ __forceinline__ unsigned short f2bf(float f) {   // RNE fp32->bf16 (setup only)
    unsigned u = __builtin_bit_cast(unsigned, f);
    u += 0x7FFF + ((u >> 16) & 1);
    return (unsigned short)(u >> 16);
}
__device__ __forceinline__ float bf2f(unsigned short b) {
    unsigned u = ((unsigned)b) << 16;
    return __builtin_bit_cast(float, u);
}
__device__ __forceinline__ float ubits(unsigned u) { return __builtin_bit_cast(float, u); }
// packed RNE fp32x2 -> bf16x2 (arg0 -> low16, arg1 -> high16)
__device__ __forceinline__ unsigned cvt_pk_bf16(float lo, float hi) {
    unsigned r;
    asm("v_cvt_pk_bf16_f32 %0, %1, %2" : "=v"(r) : "v"(lo), "v"(hi));
    return r;
}

// Spread-fused design (R4 post-mortem: trans ~16cyc/instr dominates and must be
// SPREAD over all SIMDs; R3 post-mortem: barriers+exchange idle ~600cyc/step).
// Each wave = an INDEPENDENT 4-batch recurrence (all 32 units, all 4 gates) ->
// 2048 waves = 2/SIMD on every SIMD, zero barriers ever (within-wave LDS
// ordering only). Per step: 2 b128 h-reads, 8 tiles x 3-chain MFMA from
// precomputed XC, 8 XC refill MFMAs, q==0 lanes scatter C rows 0-3 (8 b128 ->
// CV), all lanes gather their 2 cells x 4 gates (4x ds_read2-pair, 2-way
// banks), merged-rcp cell math (7 trans/cell: 5 exp + 2 rcp; single-rcp
// c-update and h), pi-packed h write (4 b16). Cell ownership batch=q, units
// (2cc,2cc+1) makes scatter/gather indices exactly bank-2-way.
__global__ void __launch_bounds__(NT, 2) lstm_spread(
    const float* __restrict__ x, const float* __restrict__ W_ih,
    const float* __restrict__ W_hh, const float* __restrict__ b_ih,
    const float* __restrict__ b_hh, const float* __restrict__ W_fc,
    const float* __restrict__ b_fc, float* __restrict__ out)
{
    __shared__ __align__(16) float CV[4][8][16][4];           // 8KB: [wv][tile][Bcol][batch]
    __shared__ __align__(16) unsigned short hh[4][16][40];    // 5KB: [wv][Arow][pi-k] (rows 4-15 stay 0)
    __shared__ __align__(16) unsigned short hl[4][16][40];    // 5KB

    const int tix  = threadIdx.x;
    const int wv   = tix >> 6;          // wave id: independent recurrence
    const int lane = tix & 63;
    const int q    = lane >> 4;         // k-quad (A/B) / C row-group / owned batch
    const int cc   = lane & 15;         // A row / B col

    // ---- static B fragments: 8 tiles t = 2*gate + half, kk pre-folded ----
    // kk: -LOG2E for i,f,o (sigmoid exps), -2*LOG2E for g (tanh exp)
    bf16x8 Bh[8], Bl[8], Bx[8];
    f32x4 biasv[8];
    #pragma unroll
    for (int t = 0; t < 8; ++t) {
        const int g = t >> 1, half = t & 1;
        const float kkg = (g == 2) ? -2.f * LOG2E : -LOG2E;
        const int r = 32 * g + 16 * half + cc;        // global gate-row
        #pragma unroll
        for (int j = 0; j < 8; ++j) {
            const int p = 8 * q + j;                  // k position (pi-order)
            const int u = 16 * (p & 1) + (p >> 1);    // unit index
            const float ws = kkg * W_hh[r * H + u];
            const unsigned short whi = f2bf(ws);
            Bh[t][j] = (short)whi;
            Bl[t][j] = (short)f2bf(ws - bf2f(whi));
            if (q == 3) {
                Bx[t][j] = 0;                          // zero k-quad
            } else {
                const float wsx = kkg * W_ih[r * IN_D + j];
                const unsigned short xwh = f2bf(wsx);
                // q=0,1 multiply x_hi/x_lo by W_hi; q=2 multiplies x_hi by W_lo
                Bx[t][j] = (q == 2) ? (short)f2bf(wsx - bf2f(xwh)) : (short)xwh;
            }
        }
        const float b = kkg * (b_ih[r] + b_hh[r]);
        biasv[t][0] = b; biasv[t][1] = b; biasv[t][2] = b; biasv[t][3] = b;
    }

    // ---- per-lane x A-frag: lane loads x[batch cc&3][t][0..7] itself ----
    const int gb = blockIdx.x * NBATCH + wv * 4;      // wave's global batch base
    const float* xp = x + (size_t)(gb + (cc & 3)) * (size_t)(T_LEN * IN_D);
    auto build = [&](float4 a, float4 b) -> bf16x8 {
        const unsigned w0 = cvt_pk_bf16(a.x, a.y);
        const unsigned w1 = cvt_pk_bf16(a.z, a.w);
        const unsigned w2 = cvt_pk_bf16(b.x, b.y);
        const unsigned w3 = cvt_pk_bf16(b.z, b.w);
        unsigned s0 = w0, s1 = w1, s2 = w2, s3 = w3;
        if (q == 1) {                                  // x_lo quad
            s0 = cvt_pk_bf16(a.x - ubits(w0 << 16), a.y - ubits(w0 & 0xffff0000u));
            s1 = cvt_pk_bf16(a.z - ubits(w1 << 16), a.w - ubits(w1 & 0xffff0000u));
            s2 = cvt_pk_bf16(b.x - ubits(w2 << 16), b.y - ubits(w2 & 0xffff0000u));
            s3 = cvt_pk_bf16(b.z - ubits(w3 << 16), b.w - ubits(w3 & 0xffff0000u));
        }
        if (q == 3) { s0 = 0; s1 = 0; s2 = 0; s3 = 0; }
        u32x4 r_ = { s0, s1, s2, s3 };
        return __builtin_bit_cast(bf16x8, r_);
    };

    // ---- init: zero h arrays (h0 = 0; rows 4-15 permanently 0) ----
    for (int i = tix; i < (int)(sizeof(hh) / 4); i += NT) {
        ((unsigned*)hh)[i] = 0u;
        ((unsigned*)hl)[i] = 0u;
    }
    __syncthreads();    // once, before the loop; never again

    // ---- prologue: XC for t=0, prefetch x[1] ----
    f32x4 XC[8];
    {
        const float4 ta = *(const float4*)(xp + 0);
        const float4 tb = *(const float4*)(xp + 4);
        const bf16x8 fr = build(ta, tb);
        #pragma unroll
        for (int t = 0; t < 8; ++t)
            XC[t] = __builtin_amdgcn_mfma_f32_16x16x32_bf16(fr, Bx[t], biasv[t], 0, 0, 0);
    }
    float4 ra = *(const float4*)(xp + IN_D);
    float4 rb = *(const float4*)(xp + IN_D + 4);

    // cell ownership: batch q, units u0=2cc, u1=2cc+1
    const int halfr = cc >> 3;            // tile half of owned units
    const int csr   = 2 * (cc & 7);       // B-col of unit u0 within tile
    const int pi0   = 4 * (cc & 7) + (cc >> 3);   // pi col of u0 (u1 -> pi0+2)
    float cs0 = 0.f, cs1 = 0.f, h0f = 0.f, h1f = 0.f;
    const float TWL = 2.f * LOG2E;

    for (int t = 0; t < T_LEN; ++t) {
        // ---- h A-frags (rows 4-15 read zeros) + 8 tiles x 3-chain MFMA ----
        const bf16x8 A0 = *(const bf16x8*)&hh[wv][cc][8 * q];
        const bf16x8 A2 = *(const bf16x8*)&hl[wv][cc][8 * q];
        f32x4 C[8];
        #pragma unroll
        for (int tt = 0; tt < 8; ++tt) {
            f32x4 a = __builtin_amdgcn_mfma_f32_16x16x32_bf16(A0, Bh[tt], XC[tt], 0, 0, 0);
            a = __builtin_amdgcn_mfma_f32_16x16x32_bf16(A2, Bh[tt], a, 0, 0, 0);
            C[tt] = __builtin_amdgcn_mfma_f32_16x16x32_bf16(A0, Bl[tt], a, 0, 0, 0);
        }

        // ---- XC refill for t+1, prefetch x[t+2] ----
        {
            const bf16x8 fr = build(ra, rb);
            #pragma unroll
            for (int tt = 0; tt < 8; ++tt)
                XC[tt] = __builtin_amdgcn_mfma_f32_16x16x32_bf16(fr, Bx[tt], biasv[tt], 0, 0, 0);
        }
        const int tn = (t + 2 < T_LEN) ? (t + 2) : (T_LEN - 1);
        ra = *(const float4*)(xp + (size_t)tn * IN_D);
        rb = *(const float4*)(xp + (size_t)tn * IN_D + 4);

        // ---- scatter: C rows 0-3 (the 4 real batches) live on q==0 lanes ----
        if (q == 0) {
            #pragma unroll
            for (int tt = 0; tt < 8; ++tt)
                *(f32x4*)&CV[wv][tt][cc][0] = C[tt];
        }

        // ---- gather: this lane's 2 cells x 4 gates (in-wave LDS ordering) ----
        float p0[4], p1[4];
        #pragma unroll
        for (int g = 0; g < 4; ++g) {
            const int tt = 2 * g + halfr;
            p0[g] = CV[wv][tt][csr][q];
            p1[g] = CV[wv][tt][csr + 1][q];
        }

        // ---- merged-rcp cell math: 5 exp + 2 rcp per cell ----
        #pragma unroll
        for (int cell = 0; cell < 2; ++cell) {
            const float Ei = fexp2(cell ? p1[0] : p0[0]);
            const float Ef = fexp2(cell ? p1[1] : p0[1]);
            const float Eg = fexp2(cell ? p1[2] : p0[2]);
            const float Eo = fexp2(cell ? p1[3] : p0[3]);
            const float P  = (1.f + Eg) * (1.f + Ei);
            const float Q  = 1.f + Ef;
            const float r1 = __builtin_fmaf(Eg, -TWL, TWL);   // 2L*(1-Eg)
            float cs = cell ? cs1 : cs0;
            const float num = __builtin_fmaf(cs, P, r1 * Q);
            const float rd  = frcp(P * Q);
            cs = num * rd;
            cs = fminf(fmaxf(cs, -CSCLAMP), CSCLAMP);
            const float W  = fexp2(cs);
            const float rh = frcp((1.f + Eo) * (W + 1.f));
            const float hv = (W - 1.f) * rh;                  // sigma(O)*tanh(c)
            if (cell) { cs1 = cs; h1f = hv; } else { cs0 = cs; h0f = hv; }
        }

        // ---- pi-packed h write: units (2cc, 2cc+1) -> pi cols (pi0, pi0+2) ----
        {
            const unsigned hw = cvt_pk_bf16(h0f, h1f);
            const unsigned lw = cvt_pk_bf16(h0f - ubits(hw << 16),
                                            h1f - ubits(hw & 0xffff0000u));
            hh[wv][q][pi0]     = (unsigned short)hw;
            hh[wv][q][pi0 + 2] = (unsigned short)(hw >> 16);
            hl[wv][q][pi0]     = (unsigned short)lw;
            hl[wv][q][pi0 + 2] = (unsigned short)(lw >> 16);
        }
        // no barrier: single-wave recurrence, LDS pipe is in-order per wave
    }

    // ---- epilogue: out[b] = h_n . W_fc + b_fc (fp32 h, reduce over cc) ----
    float sacc = h0f * W_fc[2 * cc] + h1f * W_fc[2 * cc + 1];
    sacc += __shfl_xor(sacc, 1);
    sacc += __shfl_xor(sacc, 2);
    sacc += __shfl_xor(sacc, 4);
    sacc += __shfl_xor(sacc, 8);
    if (cc == 0) out[gb + q] = sacc + b_fc[0];
}

extern "C" void kernel_launch(void* const* d_in, const int* in_sizes, int n_in,
                              void* d_out, int out_size, void* d_ws, size_t ws_size,
                              hipStream_t stream) {
    const float* x    = (const float*)d_in[0];
    const float* W_ih = (const float*)d_in[1];
    const float* W_hh = (const float*)d_in[2];
    const float* b_ih = (const float*)d_in[3];
    const float* b_hh = (const float*)d_in[4];
    const float* W_fc = (const float*)d_in[5];
    const float* b_fc = (const float*)d_in[6];
    float* out = (float*)d_out;
    const int Bn = in_sizes[0] / (T_LEN * IN_D);   // 8192
    lstm_spread<<<dim3(Bn / NBATCH), dim3(NT), 0, stream>>>(
        x, W_ih, W_hh, b_ih, b_hh, W_fc, b_fc, out);
}

// Round 6
// 473.800 us; speedup vs baseline: 1.5074x; 1.5074x over previous
//
#include <hip/hip_runtime.h>
#include <cstddef>

#define T_LEN 512
#define IN_D 8
#define H 32
#define NBATCH 16        // batches per WG (MFMA M)
#define NT 512           // 8 waves: wave w owns tile (gate g=w>>1, half d=w&1)
#define NCHUNK (T_LEN / 8)
#define LOG2E 1.44269504088896341f
#define GP 36            // G row pad (words): 144q%32=16 -> writes exact 2-way
#define CSCLAMP 88.f

typedef __attribute__((ext_vector_type(8))) short bf16x8;
typedef __attribute__((ext_vector_type(4))) float f32x4;

__device__ __forceinline__ float fexp2(float v) { return __builtin_amdgcn_exp2f(v); }
__device__ __forceinline__ float frcp(float v)  { return __builtin_amdgcn_rcpf(v); }
__device__ __forceinline__ unsigned short f2bf(float f) {   // RNE fp32->bf16 (setup only)
    unsigned u = __builtin_bit_cast(unsigned, f);
    u += 0x7FFF + ((u >> 16) & 1);
    return (unsigned short)(u >> 16);
}
__device__ __forceinline__ float bf2f(unsigned short b) {
    unsigned u = ((unsigned)b) << 16;
    return __builtin_bit_cast(float, u);
}
__device__ __forceinline__ float ubits(unsigned u) { return __builtin_bit_cast(float, u); }
// packed RNE fp32x2 -> bf16x2 (arg0 -> low16, arg1 -> high16)
__device__ __forceinline__ unsigned cvt_pk_bf16(float lo, float hi) {
    unsigned r;
    asm("v_cvt_pk_bf16_f32 %0, %1, %2" : "=v"(r) : "v"(lo), "v"(hi));
    return r;
}

// LDS-only barrier: no vmcnt drain (global x-chunk loads stay in flight).
#define WG_BARRIER() asm volatile("s_waitcnt lgkmcnt(0)\n\ts_barrier" ::: "memory")

// R3 skeleton (8 waves x one 16x16 tile, 2 barriers, XC-hoisted x path, proven
// 339us) + R5's verified merged-rcp cell math moved WHOLE to the cell thread:
// gate waves write RAW pre-activations (kk pre-folded into B: -L for i,f,o and
// -2L for g) straight from the MFMA acc to G -- zero trans in phase A. Cell
// thread: 4 gate exps + single-rcp c-update in exp2 domain + W=2^cs + single
// rcp for h = 7 trans/cell total (was 10). Trans issue is the dominant,
// partition-invariant cost (R4/R5 calibration: ~16cyc/trans at wave64).
__global__ void __launch_bounds__(NT, 4) lstm_mfma4(
    const float* __restrict__ x, const float* __restrict__ W_ih,
    const float* __restrict__ W_hh, const float* __restrict__ b_ih,
    const float* __restrict__ b_hh, const float* __restrict__ W_fc,
    const float* __restrict__ b_fc, float* __restrict__ out)
{
    __shared__ __align__(16) float G[4][NBATCH][GP];           // 9216 B, col = unit u, RAW pres
    __shared__ __align__(16) unsigned short hhi[NBATCH][48];   // 1536 B, pi-order k
    __shared__ __align__(16) unsigned short hlo[NBATCH][48];   // 1536 B
    __shared__ __align__(16) unsigned short xstg[8][17][24];   // 6528 B; cols 16-23 stay zero

    const int tix  = threadIdx.x;
    const int w    = tix >> 6;
    const int g    = w >> 1;            // gate id (0=i,1=f,2=g,3=o)
    const int d    = w & 1;             // tile half
    const int lane = tix & 63;
    const int q    = lane >> 4;         // k-quad (A/B) / row-group (C)
    const int cc   = lane & 15;         // A row (batch) / B col (unit-in-tile)

    // kk: -LOG2E for i,f,o (sigmoid exps), -2*LOG2E for g (tanh exp)
    const float kk = (g == 2) ? -2.f * LOG2E : -LOG2E;

    // ---- static B fragments for tile (g,d) (premultiplied by kk) ----
    bf16x8 Bh, Bl, Bx;
    const int r = 16 * (2 * g + d) + cc;              // global gate-row
    #pragma unroll
    for (int j = 0; j < 8; ++j) {
        const int p = 8 * q + j;                      // k position (pi-order)
        const int u = 16 * (p & 1) + (p >> 1);        // unit index
        const float ws = kk * W_hh[r * H + u];
        const unsigned short whi = f2bf(ws);
        Bh[j] = (short)whi;
        Bl[j] = (short)f2bf(ws - bf2f(whi));
        if (q == 3) {
            Bx[j] = 0;                                 // zero k-quad
        } else {
            const float wsx = kk * W_ih[r * IN_D + j];
            const unsigned short xwh = f2bf(wsx);
            // q=0,1 multiply x_hi/x_lo by W_hi; q=2 multiplies x_hi by W_lo
            Bx[j] = (q == 2) ? (short)f2bf(wsx - bf2f(xwh)) : (short)xwh;
        }
    }
    const float bias = kk * (b_ih[r] + b_hh[r]);
    const f32x4 biasv = { bias, bias, bias, bias };

    // per-lane x A-frag offset: q0->xh, q1->xl, q2->xh (again), q3->zeros
    const int xoff = (q == 2) ? 0 : ((q == 3) ? 16 : 8 * q);

    // ---- x chunk machinery (first 256 threads): (batch xb, step xs, half xhf) ----
    const int xb = (tix >> 4) & 15, xs = (tix >> 1) & 7, xhf = tix & 1;
    const bool stager = (tix < 256);
    const float* xbase = x + (size_t)(blockIdx.x * NBATCH + xb) * (size_t)(T_LEN * IN_D)
                           + xs * IN_D + 4 * xhf;
    auto ldchunk = [&](int ch) { return *(const float4*)(xbase + (size_t)ch * 8 * IN_D); };
    auto stage = [&](float4 v) {
        const unsigned h0 = cvt_pk_bf16(v.x, v.y);
        const unsigned h1 = cvt_pk_bf16(v.z, v.w);
        const unsigned l0 = cvt_pk_bf16(v.x - ubits(h0 << 16), v.y - ubits(h0 & 0xffff0000u));
        const unsigned l1 = cvt_pk_bf16(v.z - ubits(h1 << 16), v.w - ubits(h1 & 0xffff0000u));
        *(uint2*)&xstg[xs][xb][4 * xhf]     = make_uint2(h0, h1);
        *(uint2*)&xstg[xs][xb][8 + 4 * xhf] = make_uint2(l0, l1);
    };

    // ---- init: zero h and xstg (zero regions persist), stage chunk 0 ----
    for (int i = tix; i < NBATCH * 48 / 2; i += NT) {
        ((unsigned*)hhi)[i] = 0u;
        ((unsigned*)hlo)[i] = 0u;
    }
    for (int i = tix; i < 8 * 17 * 24 / 2; i += NT) ((unsigned*)xstg)[i] = 0u;
    __syncthreads();
    float4 xbuf = {0.f, 0.f, 0.f, 0.f};
    if (stager) {
        stage(ldchunk(0));
        xbuf = ldchunk(1);
    }
    __syncthreads();

    // ---- XC[s]: x-contribution + bias for this wave's tile (32 VGPRs) ----
    f32x4 XC[8];
#define REFILL(j) do { \
        const bf16x8 Ax_ = *(const bf16x8*)&xstg[(j)][cc][xoff]; \
        XC[(j)] = __builtin_amdgcn_mfma_f32_16x16x32_bf16(Ax_, Bx, biasv, 0, 0, 0); \
    } while (0)
    #pragma unroll
    for (int s = 0; s < 8; ++s) REFILL(s);

    // c/h ownership: 1 cell per thread: batch m, unit u
    const int m = tix >> 5, u = tix & 31;
    const float wfc = W_fc[u];
    const float TWL = 2.f * LOG2E;
    float cs = 0.f, hf = 0.f;

    for (int blk = 0; blk < NCHUNK; ++blk) {
        #pragma unroll
        for (int s = 0; s < 8; ++s) {
            // ---- h A-frags + 3 MFMAs (acc starts at precomputed XC) ----
            const bf16x8 A0 = *(const bf16x8*)&hhi[cc][8 * q];
            const bf16x8 A2 = *(const bf16x8*)&hlo[cc][8 * q];
            const f32x4 z = { 0.f, 0.f, 0.f, 0.f };
            f32x4 a1 = __builtin_amdgcn_mfma_f32_16x16x32_bf16(A0, Bh, XC[s], 0, 0, 0);
            f32x4 a2 = __builtin_amdgcn_mfma_f32_16x16x32_bf16(A2, Bh, z, 0, 0, 0);
            a2 = __builtin_amdgcn_mfma_f32_16x16x32_bf16(A0, Bl, a2, 0, 0, 0);
            const f32x4 C = a1 + a2;

            // ---- stage next chunk early (s==0): consumed by refills from s==1 ----
            if (s == 0 && stager) {
                stage(xbuf);
                int nc = blk + 2;
                if (nc > NCHUNK - 1) nc = NCHUNK - 1;
                xbuf = ldchunk(nc);
            }

            // ---- RAW pre-activations straight to G (no trans in phase A) ----
            #pragma unroll
            for (int rg = 0; rg < 4; ++rg)
                G[g][4 * q + rg][cc + 16 * d] = C[rg];

            // ---- spread next-chunk XC refill: 1 MFMA/step, off critical path ----
            if (s >= 1) REFILL(s - 1);
            if (s == 7) REFILL(7);

            WG_BARRIER();

            // ---- merged-rcp cell update: 7 trans total (R5-verified math) ----
            {
                const float Ei = fexp2(G[0][m][u]);
                const float Ef = fexp2(G[1][m][u]);
                const float Eg = fexp2(G[2][m][u]);
                const float Eo = fexp2(G[3][m][u]);
                const float P  = (1.f + Eg) * (1.f + Ei);
                const float Q  = 1.f + Ef;
                const float r1 = __builtin_fmaf(Eg, -TWL, TWL);   // 2L*(1-Eg)
                const float num = __builtin_fmaf(cs, P, r1 * Q);
                const float rd  = frcp(P * Q);
                cs = num * rd;                                    // cs = 2L*c
                cs = fminf(fmaxf(cs, -CSCLAMP), CSCLAMP);
                const float W  = fexp2(cs);
                const float rh = frcp((1.f + Eo) * (W + 1.f));
                hf = (W - 1.f) * rh;                              // sigma(o)*tanh(c)
                // pair (u, u+16) -> pi cols (2u', 2u'+1): partner via shfl
                const float hp = __shfl_xor(hf, 16);
                if ((tix & 16) == 0) {
                    const unsigned hw = cvt_pk_bf16(hf, hp);
                    const unsigned lw = cvt_pk_bf16(hf - ubits(hw << 16),
                                                    hp - ubits(hw & 0xffff0000u));
                    *(unsigned*)&hhi[m][2 * (u & 15)] = hw;
                    *(unsigned*)&hlo[m][2 * (u & 15)] = lw;
                }
            }

            WG_BARRIER();
        }
    }
#undef REFILL

    // ---- epilogue: out[b] = h_n . W_fc + b_fc (fp32 h, shfl reduce over u) ----
    float sacc = hf * wfc;
    sacc += __shfl_xor(sacc, 1);
    sacc += __shfl_xor(sacc, 2);
    sacc += __shfl_xor(sacc, 4);
    sacc += __shfl_xor(sacc, 8);
    sacc += __shfl_xor(sacc, 16);
    if ((tix & 31) == 0) out[blockIdx.x * NBATCH + m] = sacc + b_fc[0];
}

extern "C" void kernel_launch(void* const* d_in, const int* in_sizes, int n_in,
                              void* d_out, int out_size, void* d_ws, size_t ws_size,
                              hipStream_t stream) {
    const float* x    = (const float*)d_in[0];
    const float* W_ih = (const float*)d_in[1];
    const float* W_hh = (const float*)d_in[2];
    const float* b_ih = (const float*)d_in[3];
    const float* b_hh = (const float*)d_in[4];
    const float* W_fc = (const float*)d_in[5];
    const float* b_fc = (const float*)d_in[6];
    float* out = (float*)d_out;
    const int Bn = in_sizes[0] / (T_LEN * IN_D);   // 8192
    lstm_mfma4<<<dim3(Bn / NBATCH), dim3(NT), 0, stream>>>(
        x, W_ih, W_hh, b_ih, b_hh, W_fc, b_fc, out);
}

// Round 8
// 448.016 us; speedup vs baseline: 1.5942x; 1.0576x over previous
//
#include <hip/hip_runtime.h>
#include <cstddef>

#define T_LEN 512
#define IN_D 8
#define H 32
#define NBATCH 16        // batches per WG (MFMA M)
#define NT 512           // 8 waves: wave w owns tile (gate g=w>>1, half d=w&1)
#define NCHUNK (T_LEN / 8)
#define LOG2E 1.44269504088896341f
#define GP 36            // G row pad (words): 144q%32=16 -> writes exact 2-way

typedef __attribute__((ext_vector_type(8))) short bf16x8;
typedef __attribute__((ext_vector_type(4))) float f32x4;

__device__ __forceinline__ float fexp2(float v) { return __builtin_amdgcn_exp2f(v); }
__device__ __forceinline__ float frcp(float v)  { return __builtin_amdgcn_rcpf(v); }
__device__ __forceinline__ unsigned short f2bf(float f) {   // RNE fp32->bf16 (setup only)
    unsigned u = __builtin_bit_cast(unsigned, f);
    u += 0x7FFF + ((u >> 16) & 1);
    return (unsigned short)(u >> 16);
}
__device__ __forceinline__ float bf2f(unsigned short b) {
    unsigned u = ((unsigned)b) << 16;
    return __builtin_bit_cast(float, u);
}
__device__ __forceinline__ float ubits(unsigned u) { return __builtin_bit_cast(float, u); }
// packed RNE fp32x2 -> bf16x2 (arg0 -> low16, arg1 -> high16)
__device__ __forceinline__ unsigned cvt_pk_bf16(float lo, float hi) {
    unsigned r;
    asm("v_cvt_pk_bf16_f32 %0, %1, %2" : "=v"(r) : "v"(lo), "v"(hi));
    return r;
}

// LDS-only barrier: no vmcnt drain (global x-chunk loads stay in flight).
#define WG_BARRIER() asm volatile("s_waitcnt lgkmcnt(0)\n\ts_barrier" ::: "memory")

// R3 skeleton (8 waves x one 16x16 tile, 2 barriers, XC-hoisted x path,
// activation in phase A - proven 339us) with two chain cuts (R6 post-mortem:
// time = 512 x serial chain; issue is NOT binding):
//  (1) 3 INDEPENDENT MFMAs (a1=A0.Bh+XC, a2=A2.Bh, a3=A0.Bl; C=a1+a2+a3)
//      instead of a 2-deep MFMA chain: -1 MFMA latency off the chain.
//  (2) XC-refill's xstg ds_read hoisted ABOVE the MFMAs: previously it issued
//      right before WG_BARRIER whose lgkmcnt(0) ate its full LDS latency on
//      the chain; now it completes under the MFMA phase.
__global__ void __launch_bounds__(NT, 4) lstm_mfma4(
    const float* __restrict__ x, const float* __restrict__ W_ih,
    const float* __restrict__ W_hh, const float* __restrict__ b_ih,
    const float* __restrict__ b_hh, const float* __restrict__ W_fc,
    const float* __restrict__ b_fc, float* __restrict__ out)
{
    __shared__ __align__(16) float G[4][NBATCH][GP];           // 9216 B, col = unit u
    __shared__ __align__(16) unsigned short hhi[NBATCH][48];   // 1536 B, pi-order k
    __shared__ __align__(16) unsigned short hlo[NBATCH][48];   // 1536 B
    __shared__ __align__(16) unsigned short xstg[8][17][24];   // 6528 B; cols 16-23 stay zero

    const int tix  = threadIdx.x;
    const int w    = tix >> 6;
    const int g    = w >> 1;            // gate id (0=i,1=f,2=g,3=o)
    const int d    = w & 1;             // tile half
    const int lane = tix & 63;
    const int q    = lane >> 4;         // k-quad (A/B) / row-group (C)
    const int cc   = lane & 15;         // A row (batch) / B col (unit-in-tile)

    const float kk = (g == 2) ? 2.f * LOG2E : -LOG2E;
    const float aa = (g == 2) ? 2.f * LOG2E : 0.f;     // g stored as 2L*tanh(g)
    const float bb = (g == 2) ? -4.f * LOG2E : 1.f;

    // ---- static B fragments for tile (g,d) (premultiplied by kk) ----
    bf16x8 Bh, Bl, Bx;
    const int r = 16 * (2 * g + d) + cc;              // global gate-row
    #pragma unroll
    for (int j = 0; j < 8; ++j) {
        const int p = 8 * q + j;                      // k position (pi-order)
        const int u = 16 * (p & 1) + (p >> 1);        // unit index
        const float ws = kk * W_hh[r * H + u];
        const unsigned short whi = f2bf(ws);
        Bh[j] = (short)whi;
        Bl[j] = (short)f2bf(ws - bf2f(whi));
        if (q == 3) {
            Bx[j] = 0;                                 // zero k-quad
        } else {
            const float wsx = kk * W_ih[r * IN_D + j];
            const unsigned short xwh = f2bf(wsx);
            // q=0,1 multiply x_hi/x_lo by W_hi; q=2 multiplies x_hi by W_lo
            Bx[j] = (q == 2) ? (short)f2bf(wsx - bf2f(xwh)) : (short)xwh;
        }
    }
    const float bias = kk * (b_ih[r] + b_hh[r]);
    const f32x4 biasv = { bias, bias, bias, bias };

    // per-lane x A-frag offset: q0->xh, q1->xl, q2->xh (again), q3->zeros
    const int xoff = (q == 2) ? 0 : ((q == 3) ? 16 : 8 * q);

    // ---- x chunk machinery (first 256 threads): (batch xb, step xs, half xhf) ----
    const int xb = (tix >> 4) & 15, xs = (tix >> 1) & 7, xhf = tix & 1;
    const bool stager = (tix < 256);
    const float* xbase = x + (size_t)(blockIdx.x * NBATCH + xb) * (size_t)(T_LEN * IN_D)
                           + xs * IN_D + 4 * xhf;
    auto ldchunk = [&](int ch) { return *(const float4*)(xbase + (size_t)ch * 8 * IN_D); };
    auto stage = [&](float4 v) {
        const unsigned h0 = cvt_pk_bf16(v.x, v.y);
        const unsigned h1 = cvt_pk_bf16(v.z, v.w);
        const unsigned l0 = cvt_pk_bf16(v.x - ubits(h0 << 16), v.y - ubits(h0 & 0xffff0000u));
        const unsigned l1 = cvt_pk_bf16(v.z - ubits(h1 << 16), v.w - ubits(h1 & 0xffff0000u));
        *(uint2*)&xstg[xs][xb][4 * xhf]     = make_uint2(h0, h1);
        *(uint2*)&xstg[xs][xb][8 + 4 * xhf] = make_uint2(l0, l1);
    };

    // ---- init: zero h and xstg (zero regions persist), stage chunk 0 ----
    for (int i = tix; i < NBATCH * 48 / 2; i += NT) {
        ((unsigned*)hhi)[i] = 0u;
        ((unsigned*)hlo)[i] = 0u;
    }
    for (int i = tix; i < 8 * 17 * 24 / 2; i += NT) ((unsigned*)xstg)[i] = 0u;
    __syncthreads();
    float4 xbuf = {0.f, 0.f, 0.f, 0.f};
    if (stager) {
        stage(ldchunk(0));
        xbuf = ldchunk(1);
    }
    __syncthreads();

    // ---- XC[s]: x-contribution + bias for this wave's tile (32 VGPRs) ----
    f32x4 XC[8];
    #pragma unroll
    for (int s = 0; s < 8; ++s) {
        const bf16x8 Ax_ = *(const bf16x8*)&xstg[s][cc][xoff];
        XC[s] = __builtin_amdgcn_mfma_f32_16x16x32_bf16(Ax_, Bx, biasv, 0, 0, 0);
    }

    // c/h ownership: 1 cell per thread: batch m, unit u
    const int m = tix >> 5, u = tix & 31;
    const float wfc = W_fc[u];
    float cs = 0.f, hf = 0.f;

    for (int blk = 0; blk < NCHUNK; ++blk) {
        #pragma unroll
        for (int s = 0; s < 8; ++s) {
            // ---- all LDS reads issued up front: h A-frags + refill operands ----
            const bf16x8 A0 = *(const bf16x8*)&hhi[cc][8 * q];
            const bf16x8 A2 = *(const bf16x8*)&hlo[cc][8 * q];
            bf16x8 Axp, Ax7;
            if (s >= 1)  Axp = *(const bf16x8*)&xstg[s - 1][cc][xoff];
            if (s == 7)  Ax7 = *(const bf16x8*)&xstg[7][cc][xoff];

            // ---- 3 INDEPENDENT MFMAs (chain = 1 MFMA latency + 2 adds) ----
            const f32x4 z = { 0.f, 0.f, 0.f, 0.f };
            f32x4 a1 = __builtin_amdgcn_mfma_f32_16x16x32_bf16(A0, Bh, XC[s], 0, 0, 0);
            f32x4 a2 = __builtin_amdgcn_mfma_f32_16x16x32_bf16(A2, Bh, z, 0, 0, 0);
            f32x4 a3 = __builtin_amdgcn_mfma_f32_16x16x32_bf16(A0, Bl, z, 0, 0, 0);

            // ---- next-chunk XC refill MFMAs (off critical path, reads hoisted) ----
            if (s >= 1)
                XC[s - 1] = __builtin_amdgcn_mfma_f32_16x16x32_bf16(Axp, Bx, biasv, 0, 0, 0);
            if (s == 7)
                XC[7] = __builtin_amdgcn_mfma_f32_16x16x32_bf16(Ax7, Bx, biasv, 0, 0, 0);

            // ---- stage next chunk early (s==0): consumed by refills from s==1 ----
            if (s == 0 && stager) {
                stage(xbuf);
                int nc = blk + 2;
                if (nc > NCHUNK - 1) nc = NCHUNK - 1;
                xbuf = ldchunk(nc);
            }

            // ---- activation (kk pre-folded) -> unit-major b32 G writes ----
            const f32x4 C = (a1 + a2) + a3;
            #pragma unroll
            for (int rg = 0; rg < 4; ++rg)
                G[g][4 * q + rg][cc + 16 * d] = aa + bb * frcp(1.f + fexp2(C[rg]));

            WG_BARRIER();

            // ---- non-redundant c/h update: 1 cell/thread, exp2-domain c ----
            {
                const float gi = G[0][m][u];
                const float gf = G[1][m][u];
                const float gg = G[2][m][u];
                const float go = G[3][m][u];
                cs = gf * cs + gi * gg;               // cs = 2L*c
                const float rr = frcp(1.f + fexp2(cs));
                hf = go - 2.f * go * rr;              // o * tanh(c)
                // pair (u, u+16) -> pi cols (2u', 2u'+1): partner via shfl
                const float hp = __shfl_xor(hf, 16);
                if ((tix & 16) == 0) {
                    const unsigned hw = cvt_pk_bf16(hf, hp);
                    const unsigned lw = cvt_pk_bf16(hf - ubits(hw << 16),
                                                    hp - ubits(hw & 0xffff0000u));
                    *(unsigned*)&hhi[m][2 * (u & 15)] = hw;
                    *(unsigned*)&hlo[m][2 * (u & 15)] = lw;
                }
            }

            WG_BARRIER();
        }
    }

    // ---- epilogue: out[b] = h_n . W_fc + b_fc (fp32 h, shfl reduce over u) ----
    float sacc = hf * wfc;
    sacc += __shfl_xor(sacc, 1);
    sacc += __shfl_xor(sacc, 2);
    sacc += __shfl_xor(sacc, 4);
    sacc += __shfl_xor(sacc, 8);
    sacc += __shfl_xor(sacc, 16);
    if ((tix & 31) == 0) out[blockIdx.x * NBATCH + m] = sacc + b_fc[0];
}

extern "C" void kernel_launch(void* const* d_in, const int* in_sizes, int n_in,
                              void* d_out, int out_size, void* d_ws, size_t ws_size,
                              hipStream_t stream) {
    const float* x    = (const float*)d_in[0];
    const float* W_ih = (const float*)d_in[1];
    const float* W_hh = (const float*)d_in[2];
    const float* b_ih = (const float*)d_in[3];
    const float* b_hh = (const float*)d_in[4];
    const float* W_fc = (const float*)d_in[5];
    const float* b_fc = (const float*)d_in[6];
    float* out = (float*)d_out;
    const int Bn = in_sizes[0] / (T_LEN * IN_D);   // 8192
    lstm_mfma4<<<dim3(Bn / NBATCH), dim3(NT), 0, stream>>>(
        x, W_ih, W_hh, b_ih, b_hh, W_fc, b_fc, out);
}